// Round 5
// baseline (290.025 us; speedup 1.0000x reference)
//
#include <hip/hip_runtime.h>

#define NROWS 2097152
#define W 16
#define TPB 256
#define BLOCKS 4096
#define NTHREADS (BLOCKS * TPB)            // 1,048,576 threads
#define RPT (NROWS / NTHREADS)             // 2 rows per thread — exact, no tail

typedef float f32x4 __attribute__((ext_vector_type(4)));

// Tree argmax over 16 values: depth-4 fmaxf tree + parallel equality mask.
// __ffs picks the FIRST matching index -> matches jnp.argmax tie-break.
__device__ __forceinline__ int argmax16(const float* v, float& mout)
{
    float a0 = fmaxf(v[0],  v[1]),  a1 = fmaxf(v[2],  v[3]);
    float a2 = fmaxf(v[4],  v[5]),  a3 = fmaxf(v[6],  v[7]);
    float a4 = fmaxf(v[8],  v[9]),  a5 = fmaxf(v[10], v[11]);
    float a6 = fmaxf(v[12], v[13]), a7 = fmaxf(v[14], v[15]);
    float b0 = fmaxf(a0, a1), b1 = fmaxf(a2, a3);
    float b2 = fmaxf(a4, a5), b3 = fmaxf(a6, a7);
    float m  = fmaxf(fmaxf(b0, b1), fmaxf(b2, b3));
    unsigned mask = 0u;
#pragma unroll
    for (int j = 0; j < 16; ++j) mask |= (v[j] == m) ? (1u << j) : 0u;
    mout = m;
    return __ffs(mask) - 1;
}

__global__ __launch_bounds__(TPB) void cel_weight_kernel(
    const float* __restrict__ predict,
    const float* __restrict__ target,
    const float* __restrict__ penalty,
    float* __restrict__ out)
{
    __shared__ float s_pen[W * W];
    __shared__ float s_part[TPB / 64];

    const int tid = threadIdx.x;
    s_pen[tid] = penalty[tid];          // TPB == 256 == W*W: one element each
    __syncthreads();

    const int gid = blockIdx.x * TPB + tid;

    // Nontemporal (skip L1 alloc) + issue ALL 16 dwordx4 before any compute.
    // Order: row0-predict, row0-target, row1-predict, row1-target — so the
    // compiler's partial vmcnt lets row-0 compute overlap row-1's loads.
    f32x4 pb[RPT][4], tb[RPT][4];
#pragma unroll
    for (int k = 0; k < RPT; ++k) {
        const f32x4* prow = (const f32x4*)predict + (size_t)(gid + k * NTHREADS) * 4;
        const f32x4* trow = (const f32x4*)target  + (size_t)(gid + k * NTHREADS) * 4;
#pragma unroll
        for (int j = 0; j < 4; ++j) pb[k][j] = __builtin_nontemporal_load(&prow[j]);
#pragma unroll
        for (int j = 0; j < 4; ++j) tb[k][j] = __builtin_nontemporal_load(&trow[j]);
    }
    // Pin the schedule: loads may NOT be sunk past this point. This is what
    // round 3 was missing (compiler re-interleaved to save VGPRs, killing MLP).
    __builtin_amdgcn_sched_barrier(0);

    float acc = 0.0f;

#pragma unroll
    for (int k = 0; k < RPT; ++k) {
        float pv[W], tv[W];
#pragma unroll
        for (int j = 0; j < 4; ++j) {
#pragma unroll
            for (int e = 0; e < 4; ++e) {
                pv[j * 4 + e] = pb[k][j][e];
                tv[j * 4 + e] = tb[k][j][e];
            }
        }

        float pmax, tmax;
        const int pidx = argmax16(pv, pmax);
        const int tidx = argmax16(tv, tmax);

        // softmax denominator; numerator at argmax is exp(0)=1
        float s = 0.0f;
#pragma unroll
        for (int j = 0; j < W; ++j) s += __expf(pv[j] - pmax);

        const float w = s_pen[tidx * W + pidx];
        acc += (pidx == tidx) ? 0.0f : w / s;
    }

    // wave-64 reduction
#pragma unroll
    for (int off = 32; off > 0; off >>= 1)
        acc += __shfl_down(acc, off);

    const int lane = tid & 63;
    const int wid  = tid >> 6;
    if (lane == 0) s_part[wid] = acc;
    __syncthreads();

    if (tid == 0) {
        float tot = s_part[0] + s_part[1] + s_part[2] + s_part[3];
        atomicAdd(out, tot * (1.0f / (float)NROWS));
    }
}

extern "C" void kernel_launch(void* const* d_in, const int* in_sizes, int n_in,
                              void* d_out, int out_size, void* d_ws, size_t ws_size,
                              hipStream_t stream)
{
    const float* predict = (const float*)d_in[0];
    const float* target  = (const float*)d_in[1];
    const float* penalty = (const float*)d_in[2];
    float* out = (float*)d_out;

    // d_out is poisoned (0xAA) before every replay — zero it on-stream.
    hipMemsetAsync(out, 0, sizeof(float) * out_size, stream);

    dim3 grid(BLOCKS), block(TPB);
    cel_weight_kernel<<<grid, block, 0, stream>>>(predict, target, penalty, out);
}

// Round 6
// 278.662 us; speedup vs baseline: 1.0408x; 1.0408x over previous
//
#include <hip/hip_runtime.h>

#define NROWS 2097152
#define W 16
#define TPB 256
#define BLOCKS 2048
#define NTHREADS (BLOCKS * TPB)            // 524,288 threads
#define RPT (NROWS / NTHREADS)             // 4 rows per thread — exact, no tail

typedef float f32x4 __attribute__((ext_vector_type(4)));

// Tree argmax over 16 values: depth-4 fmaxf tree + parallel equality mask.
// __ffs picks the FIRST matching index -> matches jnp.argmax tie-break.
__device__ __forceinline__ int argmax16(const float* v, float& mout)
{
    float a0 = fmaxf(v[0],  v[1]),  a1 = fmaxf(v[2],  v[3]);
    float a2 = fmaxf(v[4],  v[5]),  a3 = fmaxf(v[6],  v[7]);
    float a4 = fmaxf(v[8],  v[9]),  a5 = fmaxf(v[10], v[11]);
    float a6 = fmaxf(v[12], v[13]), a7 = fmaxf(v[14], v[15]);
    float b0 = fmaxf(a0, a1), b1 = fmaxf(a2, a3);
    float b2 = fmaxf(a4, a5), b3 = fmaxf(a6, a7);
    float m  = fmaxf(fmaxf(b0, b1), fmaxf(b2, b3));
    unsigned mask = 0u;
#pragma unroll
    for (int j = 0; j < 16; ++j) mask |= (v[j] == m) ? (1u << j) : 0u;
    mout = m;
    return __ffs(mask) - 1;
}

// Nontemporal row load: skip L1 allocation (streaming data, zero reuse).
__device__ __forceinline__ void load_row(const f32x4* __restrict__ base, int r,
                                         f32x4 v[4])
{
    const f32x4* p = base + (size_t)r * 4;
#pragma unroll
    for (int j = 0; j < 4; ++j) v[j] = __builtin_nontemporal_load(&p[j]);
}

__device__ __forceinline__ float row_term(const f32x4 p[4], const f32x4 t[4],
                                          const float* __restrict__ s_pen)
{
    float pv[W], tv[W];
#pragma unroll
    for (int j = 0; j < 4; ++j)
#pragma unroll
        for (int e = 0; e < 4; ++e) {
            pv[4 * j + e] = p[j][e];
            tv[4 * j + e] = t[j][e];
        }
    float pmax, tmax;
    const int pidx = argmax16(pv, pmax);
    const int tidx = argmax16(tv, tmax);
    // softmax denominator; numerator at argmax is exp(0)=1
    float s = 0.0f;
#pragma unroll
    for (int j = 0; j < W; ++j) s += __expf(pv[j] - pmax);
    return (pidx == tidx) ? 0.0f : s_pen[tidx * W + pidx] / s;
}

__global__ __launch_bounds__(TPB, 4) void cel_weight_kernel(
    const float* __restrict__ predict,
    const float* __restrict__ target,
    const float* __restrict__ penalty,
    float* __restrict__ out)
{
    __shared__ float s_pen[W * W];
    __shared__ float s_part[TPB / 64];

    const int tid = threadIdx.x;
    s_pen[tid] = penalty[tid];          // TPB == 256 == W*W: one element each
    __syncthreads();

    const int gid = blockIdx.x * TPB + tid;
    const f32x4* __restrict__ P4 = (const f32x4*)predict;
    const f32x4* __restrict__ T4 = (const f32x4*)target;

    // Register ping-pong pipeline (static names — no runtime indexing):
    // every compute overlaps 8 outstanding nt loads; no full vmcnt drains.
    f32x4 pA[4], tA[4], pB[4], tB[4];

    load_row(P4, gid + 0 * NTHREADS, pA);
    load_row(T4, gid + 0 * NTHREADS, tA);
    load_row(P4, gid + 1 * NTHREADS, pB);
    load_row(T4, gid + 1 * NTHREADS, tB);

    float acc = 0.0f;
    acc += row_term(pA, tA, s_pen);      // waits A only; B stays in flight

    load_row(P4, gid + 2 * NTHREADS, pA);
    load_row(T4, gid + 2 * NTHREADS, tA);
    acc += row_term(pB, tB, s_pen);      // waits B; new A in flight

    load_row(P4, gid + 3 * NTHREADS, pB);
    load_row(T4, gid + 3 * NTHREADS, tB);
    acc += row_term(pA, tA, s_pen);      // waits A; new B in flight

    acc += row_term(pB, tB, s_pen);

    // wave-64 reduction
#pragma unroll
    for (int off = 32; off > 0; off >>= 1)
        acc += __shfl_down(acc, off);

    const int lane = tid & 63;
    const int wid  = tid >> 6;
    if (lane == 0) s_part[wid] = acc;
    __syncthreads();

    if (tid == 0) {
        float tot = s_part[0] + s_part[1] + s_part[2] + s_part[3];
        atomicAdd(out, tot * (1.0f / (float)NROWS));
    }
}

extern "C" void kernel_launch(void* const* d_in, const int* in_sizes, int n_in,
                              void* d_out, int out_size, void* d_ws, size_t ws_size,
                              hipStream_t stream)
{
    const float* predict = (const float*)d_in[0];
    const float* target  = (const float*)d_in[1];
    const float* penalty = (const float*)d_in[2];
    float* out = (float*)d_out;

    // d_out is poisoned (0xAA) before every replay — zero it on-stream.
    hipMemsetAsync(out, 0, sizeof(float) * out_size, stream);

    dim3 grid(BLOCKS), block(TPB);
    cel_weight_kernel<<<grid, block, 0, stream>>>(predict, target, penalty, out);
}